// Round 1
// baseline (1457.303 us; speedup 1.0000x reference)
//
#include <hip/hip_runtime.h>

#define N_NODES 100000
#define N_EDGES 1600000
#define D 128
#define NLAYER 3

// ---------------------------------------------------------------- utility
__global__ void k_zero_i32(int* __restrict__ p, int n) {
    int i = blockIdx.x * blockDim.x + threadIdx.x;
    if (i < n) p[i] = 0;
}

// ---------------------------------------------------------------- CSR build
__global__ void k_hist(const int* __restrict__ dst, int* __restrict__ deg, int e) {
    int i = blockIdx.x * blockDim.x + threadIdx.x;
    if (i < e) atomicAdd(&deg[dst[i]], 1);
}

// 1024 elements per block (256 threads x 4 consecutive)
__global__ void k_scan_partial(const int* __restrict__ deg, int* __restrict__ bsum, int n) {
    __shared__ int sd[256];
    int tid  = threadIdx.x;
    int base = blockIdx.x * 1024 + tid * 4;
    int s = 0;
    #pragma unroll
    for (int j = 0; j < 4; ++j) {
        int idx = base + j;
        if (idx < n) s += deg[idx];
    }
    sd[tid] = s;
    __syncthreads();
    for (int o = 128; o > 0; o >>= 1) {
        if (tid < o) sd[tid] += sd[tid + o];
        __syncthreads();
    }
    if (tid == 0) bsum[blockIdx.x] = sd[0];
}

// exclusive scan of <=128 block sums, in place
__global__ void k_scan_top(int* __restrict__ bsum, int nb) {
    __shared__ int sd[128];
    int tid = threadIdx.x;
    int v = (tid < nb) ? bsum[tid] : 0;
    sd[tid] = v;
    __syncthreads();
    int tot = v;
    for (int o = 1; o < 128; o <<= 1) {
        int t = (tid >= o) ? sd[tid - o] : 0;
        __syncthreads();
        sd[tid] += t;
        __syncthreads();
    }
    if (tid < nb) bsum[tid] = sd[tid] - tot;  // exclusive
}

__global__ void k_scan_final(const int* __restrict__ deg, const int* __restrict__ bofs,
                             int* __restrict__ offs, int* __restrict__ cursor, int n) {
    __shared__ int sd[256];
    int tid  = threadIdx.x;
    int base = blockIdx.x * 1024 + tid * 4;
    int v[4];
    int s = 0;
    #pragma unroll
    for (int j = 0; j < 4; ++j) {
        int idx = base + j;
        v[j] = (idx < n) ? deg[idx] : 0;
        s += v[j];
    }
    sd[tid] = s;
    __syncthreads();
    int own = s;
    for (int o = 1; o < 256; o <<= 1) {
        int t = (tid >= o) ? sd[tid - o] : 0;
        __syncthreads();
        sd[tid] += t;
        __syncthreads();
    }
    int excl = sd[tid] - own + bofs[blockIdx.x];
    #pragma unroll
    for (int j = 0; j < 4; ++j) {
        int idx = base + j;
        if (idx < n) { offs[idx] = excl; cursor[idx] = excl; }
        excl += v[j];
    }
}

__global__ void k_scatter(const int* __restrict__ src, const int* __restrict__ dst,
                          int* __restrict__ cursor, int* __restrict__ csrc, int e) {
    int i = blockIdx.x * blockDim.x + threadIdx.x;
    if (i < e) {
        int d = dst[i];
        int p = atomicAdd(&cursor[d], 1);
        csrc[p] = src[i];
    }
}

// ---------------------------------------------------------------- aggregation
// z[i,:] = h[i,:] + sum_{e: dst==i} h[src[e],:]   (one wave per node, float2/lane)
__global__ __launch_bounds__(256)
void k_agg(const float* __restrict__ h, const int* __restrict__ offs,
           const int* __restrict__ deg, const int* __restrict__ csrc,
           float* __restrict__ out, int n) {
    int node = blockIdx.x * 4 + (threadIdx.x >> 6);
    if (node >= n) return;
    int lane = threadIdx.x & 63;
    const float2* hp = (const float2*)h;
    float2 acc = hp[node * 64 + lane];
    int s = offs[node];
    int d = deg[node];
    for (int j = 0; j < d; ++j) {
        int nb = csrc[s + j];
        float2 v = hp[nb * 64 + lane];
        acc.x += v.x;
        acc.y += v.y;
    }
    ((float2*)out)[node * 64 + lane] = acc;
}

// ---------------------------------------------------------------- GEMM (+ fused BN stats)
// C[n x 128] = preaffine(A)[n x 128] @ W[128 x 128] + bias
// preaffine (if pre_scale != null): a -> relu(a*pre_scale[k] + pre_shift[k])
// stats[0..127] += column sums of C (valid rows), stats[128..255] += column sumsq
#define BM 64
#define KC 64
__global__ __launch_bounds__(256)
void k_gemm(const float* __restrict__ A, const float* __restrict__ W,
            const float* __restrict__ bias,
            const float* __restrict__ pre_scale, const float* __restrict__ pre_shift,
            float* __restrict__ C, float* __restrict__ stats, int n) {
    __shared__ float At[KC][BM + 1];   // [k][r], +1 pad
    __shared__ float Ws[KC][D];        // [k][c], float4-contiguous reads
    __shared__ float red[2 * D];

    int tid  = threadIdx.x;
    int tx   = tid & 31;    // col group: cols tx*4 .. tx*4+3
    int ty   = tid >> 5;    // row group: rows ty*8 .. ty*8+7
    int row0 = blockIdx.x * BM;

    float acc[8][4];
    #pragma unroll
    for (int i = 0; i < 8; ++i)
        #pragma unroll
        for (int j = 0; j < 4; ++j) acc[i][j] = 0.f;

    int cA = tid & 63;   // k offset within chunk for staging
    int rA = tid >> 6;   // row base (step 4) for staging

    for (int kc = 0; kc < D; kc += KC) {
        // --- stage A (transposed, with optional BN+ReLU pre-affine) ---
        float sc = 1.f, sh = 0.f;
        if (pre_scale) { sc = pre_scale[kc + cA]; sh = pre_shift[kc + cA]; }
        #pragma unroll
        for (int i = 0; i < 16; ++i) {
            int r    = rA + i * 4;
            int grow = row0 + r;
            float v  = 0.f;
            if (grow < n) v = A[grow * D + kc + cA];
            if (pre_scale) { v = v * sc + sh; v = v > 0.f ? v : 0.f; }
            At[cA][r] = v;
        }
        // --- stage W chunk (64 x 128) ---
        #pragma unroll
        for (int j = 0; j < 8; ++j) {
            int idx = tid + j * 256;       // float4 id, 0..2047
            int wr  = idx >> 5;            // 0..63
            int wc  = (idx & 31) << 2;     // 0..124
            *(float4*)&Ws[wr][wc] = *(const float4*)&W[(kc + wr) * D + wc];
        }
        __syncthreads();
        // --- inner product ---
        #pragma unroll 8
        for (int k = 0; k < KC; ++k) {
            float4 w = *(const float4*)&Ws[k][tx << 2];
            float a[8];
            #pragma unroll
            for (int i = 0; i < 8; ++i) a[i] = At[k][(ty << 3) + i];
            #pragma unroll
            for (int i = 0; i < 8; ++i) {
                acc[i][0] += a[i] * w.x;
                acc[i][1] += a[i] * w.y;
                acc[i][2] += a[i] * w.z;
                acc[i][3] += a[i] * w.w;
            }
        }
        __syncthreads();
    }

    // --- epilogue: bias, store, fused BN statistics ---
    float4 b4 = *(const float4*)&bias[tx << 2];
    float s0 = 0, s1 = 0, s2 = 0, s3 = 0;
    float q0 = 0, q1 = 0, q2 = 0, q3 = 0;
    #pragma unroll
    for (int i = 0; i < 8; ++i) {
        int grow = row0 + (ty << 3) + i;
        if (grow < n) {
            float4 o;
            o.x = acc[i][0] + b4.x;
            o.y = acc[i][1] + b4.y;
            o.z = acc[i][2] + b4.z;
            o.w = acc[i][3] + b4.w;
            *(float4*)&C[grow * D + (tx << 2)] = o;
            s0 += o.x; s1 += o.y; s2 += o.z; s3 += o.w;
            q0 += o.x * o.x; q1 += o.y * o.y; q2 += o.z * o.z; q3 += o.w * o.w;
        }
    }
    red[tid] = 0.f;  // 256 entries = sum[128] | sumsq[128]
    __syncthreads();
    int c0 = tx << 2;
    atomicAdd(&red[c0 + 0], s0); atomicAdd(&red[c0 + 1], s1);
    atomicAdd(&red[c0 + 2], s2); atomicAdd(&red[c0 + 3], s3);
    atomicAdd(&red[D + c0 + 0], q0); atomicAdd(&red[D + c0 + 1], q1);
    atomicAdd(&red[D + c0 + 2], q2); atomicAdd(&red[D + c0 + 3], q3);
    __syncthreads();
    atomicAdd(&stats[tid], red[tid]);
}

// ---------------------------------------------------------------- BN param fold
__global__ void k_bnparams(const float* __restrict__ stats, const float* __restrict__ gamma,
                           const float* __restrict__ beta, float* __restrict__ scale,
                           float* __restrict__ shift, float inv_n) {
    int c = threadIdx.x;  // 128 threads
    float mu  = stats[c] * inv_n;
    float var = stats[D + c] * inv_n - mu * mu;
    var = var < 0.f ? 0.f : var;
    float rs = rsqrtf(var + 1e-5f);
    float sc = gamma[c] * rs;
    scale[c] = sc;
    shift[c] = beta[c] - mu * sc;
}

// ---------------------------------------------------------------- BN apply (+relu)
__global__ __launch_bounds__(256)
void k_final(const float* __restrict__ z, const float* __restrict__ scale,
             const float* __restrict__ shift, int relu, float* __restrict__ out, int total4) {
    int i = blockIdx.x * blockDim.x + threadIdx.x;
    if (i >= total4) return;
    float4 v = ((const float4*)z)[i];
    int c = (i << 2) & (D - 1);
    v.x = v.x * scale[c + 0] + shift[c + 0];
    v.y = v.y * scale[c + 1] + shift[c + 1];
    v.z = v.z * scale[c + 2] + shift[c + 2];
    v.w = v.w * scale[c + 3] + shift[c + 3];
    if (relu) {
        v.x = v.x > 0.f ? v.x : 0.f;
        v.y = v.y > 0.f ? v.y : 0.f;
        v.z = v.z > 0.f ? v.z : 0.f;
        v.w = v.w > 0.f ? v.w : 0.f;
    }
    ((float4*)out)[i] = v;
}

// ---------------------------------------------------------------- launch
extern "C" void kernel_launch(void* const* d_in, const int* in_sizes, int n_in,
                              void* d_out, int out_size, void* d_ws, size_t ws_size,
                              hipStream_t stream) {
    const float* x   = (const float*)d_in[0];
    const int*   ei  = (const int*)d_in[1];
    const float* W1  = (const float*)d_in[4];
    const float* b1  = (const float*)d_in[5];
    const float* g1  = (const float*)d_in[6];
    const float* be1 = (const float*)d_in[7];
    const float* W2  = (const float*)d_in[8];
    const float* b2  = (const float*)d_in[9];
    const float* g2  = (const float*)d_in[10];
    const float* be2 = (const float*)d_in[11];

    const int* srcI = ei;             // edge_index[0]
    const int* dstI = ei + N_EDGES;   // edge_index[1]

    // workspace layout (~110 MB)
    char* ws = (char*)d_ws;
    float* buf0  = (float*)ws; ws += (size_t)N_NODES * D * 4;
    float* buf1  = (float*)ws; ws += (size_t)N_NODES * D * 4;
    int* csrc    = (int*)ws;   ws += (size_t)N_EDGES * 4;
    int* deg     = (int*)ws;   ws += (size_t)N_NODES * 4;
    int* offs    = (int*)ws;   ws += (size_t)N_NODES * 4;
    int* cursor  = (int*)ws;   ws += (size_t)N_NODES * 4;
    int* bsum    = (int*)ws;   ws += 512;
    float* stats = (float*)ws; ws += 1024;
    float* scale1 = (float*)ws; ws += 512;
    float* shift1 = (float*)ws; ws += 512;
    float* scale2 = (float*)ws; ws += 512;
    float* shift2 = (float*)ws; ws += 512;

    // ---- CSR build (edge_index constant across layers) ----
    k_zero_i32<<<(N_NODES + 255) / 256, 256, 0, stream>>>(deg, N_NODES);
    k_hist<<<(N_EDGES + 255) / 256, 256, 0, stream>>>(dstI, deg, N_EDGES);
    int nsb = (N_NODES + 1023) / 1024;  // 98
    k_scan_partial<<<nsb, 256, 0, stream>>>(deg, bsum, N_NODES);
    k_scan_top<<<1, 128, 0, stream>>>(bsum, nsb);
    k_scan_final<<<nsb, 256, 0, stream>>>(deg, bsum, offs, cursor, N_NODES);
    k_scatter<<<(N_EDGES + 255) / 256, 256, 0, stream>>>(srcI, dstI, cursor, csrc, N_EDGES);

    float* out = (float*)d_out;
    const float* h = x;
    float* A = buf0;
    float* B = buf1;
    const float inv_n = 1.0f / (float)N_NODES;

    for (int l = 0; l < NLAYER; ++l) {
        // z0 = h + segment_sum(h[src], dst)
        k_agg<<<(N_NODES + 3) / 4, 256, 0, stream>>>(h, offs, deg, csrc, A, N_NODES);
        // z1 = z0 @ W1 + b1 (fused col stats)
        k_zero_i32<<<1, 256, 0, stream>>>((int*)stats, 256);
        k_gemm<<<(N_NODES + BM - 1) / BM, 256, 0, stream>>>(
            A, W1 + (size_t)l * D * D, b1 + l * D, nullptr, nullptr, B, stats, N_NODES);
        k_bnparams<<<1, D, 0, stream>>>(stats, g1 + l * D, be1 + l * D, scale1, shift1, inv_n);
        // z2 = relu(bn1(z1)) @ W2 + b2 (pre-affine fused into A staging; fused col stats)
        k_zero_i32<<<1, 256, 0, stream>>>((int*)stats, 256);
        float* z2 = (l == NLAYER - 1) ? out : A;
        k_gemm<<<(N_NODES + BM - 1) / BM, 256, 0, stream>>>(
            B, W2 + (size_t)l * D * D, b2 + l * D, scale1, shift1, z2, stats, N_NODES);
        k_bnparams<<<1, D, 0, stream>>>(stats, g2 + l * D, be2 + l * D, scale2, shift2, inv_n);
        // h' = bn2(z2) (+relu except last); in-place
        float* hn = z2;
        k_final<<<(N_NODES * D / 4 + 255) / 256, 256, 0, stream>>>(
            z2, scale2, shift2, (l < NLAYER - 1) ? 1 : 0, hn, N_NODES * D / 4);
        h = hn;
        float* tmp = A; A = B; B = tmp;
    }
}

// Round 3
// 867.618 us; speedup vs baseline: 1.6797x; 1.6797x over previous
//
#include <hip/hip_runtime.h>

#define N_NODES 100000
#define N_EDGES 1600000
#define D 128
#define NLAYER 3
#define NSLOT 8

typedef __bf16 bf16x8 __attribute__((ext_vector_type(8)));
typedef float f32x4 __attribute__((ext_vector_type(4)));

__device__ inline ushort f2b(float f) {
    union { float f; unsigned u; } v; v.f = f;
    unsigned u = v.u;
    return (ushort)((u + 0x7FFFu + ((u >> 16) & 1u)) >> 16);  // RNE
}
__device__ inline float b2f_lo(unsigned u) {
    union { unsigned u; float f; } v; v.u = u << 16; return v.f;
}
__device__ inline float b2f_hi(unsigned u) {
    union { unsigned u; float f; } v; v.u = u & 0xFFFF0000u; return v.f;
}

// ---------------------------------------------------------------- utility
__global__ void k_zero_i32(int* __restrict__ p, int n) {
    int i = blockIdx.x * blockDim.x + threadIdx.x;
    if (i < n) p[i] = 0;
}

// ---------------------------------------------------------------- CSR build
__global__ void k_hist(const int* __restrict__ dst, int* __restrict__ deg, int e) {
    int i = blockIdx.x * blockDim.x + threadIdx.x;
    if (i < e) atomicAdd(&deg[dst[i]], 1);
}

__global__ void k_scan_partial(const int* __restrict__ deg, int* __restrict__ bsum, int n) {
    __shared__ int sd[256];
    int tid  = threadIdx.x;
    int base = blockIdx.x * 1024 + tid * 4;
    int s = 0;
    #pragma unroll
    for (int j = 0; j < 4; ++j) {
        int idx = base + j;
        if (idx < n) s += deg[idx];
    }
    sd[tid] = s;
    __syncthreads();
    for (int o = 128; o > 0; o >>= 1) {
        if (tid < o) sd[tid] += sd[tid + o];
        __syncthreads();
    }
    if (tid == 0) bsum[blockIdx.x] = sd[0];
}

__global__ void k_scan_top(int* __restrict__ bsum, int nb) {
    __shared__ int sd[128];
    int tid = threadIdx.x;
    int v = (tid < nb) ? bsum[tid] : 0;
    sd[tid] = v;
    __syncthreads();
    int tot = v;
    for (int o = 1; o < 128; o <<= 1) {
        int t = (tid >= o) ? sd[tid - o] : 0;
        __syncthreads();
        sd[tid] += t;
        __syncthreads();
    }
    if (tid < nb) bsum[tid] = sd[tid] - tot;  // exclusive
}

__global__ void k_scan_final(const int* __restrict__ deg, const int* __restrict__ bofs,
                             int* __restrict__ offs, int* __restrict__ cursor, int n) {
    __shared__ int sd[256];
    int tid  = threadIdx.x;
    int base = blockIdx.x * 1024 + tid * 4;
    int v[4];
    int s = 0;
    #pragma unroll
    for (int j = 0; j < 4; ++j) {
        int idx = base + j;
        v[j] = (idx < n) ? deg[idx] : 0;
        s += v[j];
    }
    sd[tid] = s;
    __syncthreads();
    int own = s;
    for (int o = 1; o < 256; o <<= 1) {
        int t = (tid >= o) ? sd[tid - o] : 0;
        __syncthreads();
        sd[tid] += t;
        __syncthreads();
    }
    int excl = sd[tid] - own + bofs[blockIdx.x];
    #pragma unroll
    for (int j = 0; j < 4; ++j) {
        int idx = base + j;
        if (idx < n) { offs[idx] = excl; cursor[idx] = excl; }
        excl += v[j];
    }
}

__global__ void k_scatter(const int* __restrict__ src, const int* __restrict__ dst,
                          int* __restrict__ cursor, int* __restrict__ csrc, int e) {
    int i = blockIdx.x * blockDim.x + threadIdx.x;
    if (i < e) {
        int d = dst[i];
        int p = atomicAdd(&cursor[d], 1);
        csrc[p] = src[i];
    }
}

// ---------------------------------------------------------------- aggregation
// out[i,:] = bf16( h[i,:] + sum_j h[src_j,:] ).  One wave per node.
__global__ __launch_bounds__(256)
void k_agg_f32(const float* __restrict__ h, const int* __restrict__ offs,
               const int* __restrict__ deg, const int* __restrict__ csrc,
               unsigned* __restrict__ out, int n) {
    int node = blockIdx.x * 4 + (threadIdx.x >> 6);
    if (node >= n) return;
    int lane = threadIdx.x & 63;
    const float2* hp = (const float2*)h;
    float2 acc = hp[node * 64 + lane];
    int s = offs[node], d = deg[node];
    for (int c = 0; c < d; c += 64) {
        int m = min(64, d - c);
        int myi = (lane < m) ? csrc[s + c + lane] : 0;
        int j = 0;
        for (; j + 4 <= m; j += 4) {
            int n0 = __shfl(myi, j + 0), n1 = __shfl(myi, j + 1);
            int n2 = __shfl(myi, j + 2), n3 = __shfl(myi, j + 3);
            float2 v0 = hp[n0 * 64 + lane];
            float2 v1 = hp[n1 * 64 + lane];
            float2 v2 = hp[n2 * 64 + lane];
            float2 v3 = hp[n3 * 64 + lane];
            acc.x += v0.x + v1.x + v2.x + v3.x;
            acc.y += v0.y + v1.y + v2.y + v3.y;
        }
        for (; j < m; ++j) {
            int nb = __shfl(myi, j);
            float2 v = hp[nb * 64 + lane];
            acc.x += v.x; acc.y += v.y;
        }
    }
    out[node * 64 + lane] = (unsigned)f2b(acc.x) | ((unsigned)f2b(acc.y) << 16);
}

__global__ __launch_bounds__(256)
void k_agg_b16(const unsigned* __restrict__ h, const int* __restrict__ offs,
               const int* __restrict__ deg, const int* __restrict__ csrc,
               unsigned* __restrict__ out, int n) {
    int node = blockIdx.x * 4 + (threadIdx.x >> 6);
    if (node >= n) return;
    int lane = threadIdx.x & 63;
    unsigned u = h[node * 64 + lane];
    float ax = b2f_lo(u), ay = b2f_hi(u);
    int s = offs[node], d = deg[node];
    for (int c = 0; c < d; c += 64) {
        int m = min(64, d - c);
        int myi = (lane < m) ? csrc[s + c + lane] : 0;
        int j = 0;
        for (; j + 4 <= m; j += 4) {
            int n0 = __shfl(myi, j + 0), n1 = __shfl(myi, j + 1);
            int n2 = __shfl(myi, j + 2), n3 = __shfl(myi, j + 3);
            unsigned u0 = h[n0 * 64 + lane];
            unsigned u1 = h[n1 * 64 + lane];
            unsigned u2 = h[n2 * 64 + lane];
            unsigned u3 = h[n3 * 64 + lane];
            ax += b2f_lo(u0) + b2f_lo(u1) + b2f_lo(u2) + b2f_lo(u3);
            ay += b2f_hi(u0) + b2f_hi(u1) + b2f_hi(u2) + b2f_hi(u3);
        }
        for (; j < m; ++j) {
            int nb = __shfl(myi, j);
            unsigned uu = h[nb * 64 + lane];
            ax += b2f_lo(uu); ay += b2f_hi(uu);
        }
    }
    out[node * 64 + lane] = (unsigned)f2b(ax) | ((unsigned)f2b(ay) << 16);
}

// ---------------------------------------------------------------- weight prep
// W fp32 [3][k=128][n=128] -> Wt bf16 [3][n=128][k=128]
__global__ void k_wprep(const float* __restrict__ W, ushort* __restrict__ Wt) {
    int m = blockIdx.y, nn = blockIdx.x, k = threadIdx.x;
    float v = W[(m * D + k) * D + nn];
    Wt[(m * D + nn) * D + k] = f2b(v);
}

// ---------------------------------------------------------------- MFMA GEMM + fused BN stats
__device__ inline bf16x8 load_frag(const ushort* __restrict__ A, int row, int kb, int n,
                                   const float* __restrict__ ps, const float* __restrict__ psh) {
    bf16x8 r;
    if (row >= n) {
        #pragma unroll
        for (int j = 0; j < 8; ++j) r[j] = (__bf16)0.0f;
        return r;
    }
    if (!ps) return *(const bf16x8*)&A[(size_t)row * D + kb];
    unsigned u[4];
    *(uint4*)u = *(const uint4*)&A[(size_t)row * D + kb];
    #pragma unroll
    for (int p = 0; p < 4; ++p) {
        float lo = b2f_lo(u[p]) * ps[kb + 2 * p] + psh[kb + 2 * p];
        float hi = b2f_hi(u[p]) * ps[kb + 2 * p + 1] + psh[kb + 2 * p + 1];
        lo = lo > 0.f ? lo : 0.f;
        hi = hi > 0.f ? hi : 0.f;
        r[2 * p] = (__bf16)lo;
        r[2 * p + 1] = (__bf16)hi;
    }
    return r;
}

__global__ __launch_bounds__(256)
void k_gemm(const ushort* __restrict__ A, const ushort* __restrict__ Wt,
            const float* __restrict__ bias,
            const float* __restrict__ pre_scale, const float* __restrict__ pre_shift,
            ushort* __restrict__ C, float* __restrict__ stats, int n) {
    __shared__ ushort WtS[128 * 136];  // row stride 136 ushorts = 272 B (17x16B)

    // stage Wt (32 KB = 2048 uint4, 16 per row) coalesced
    const uint4* wsrc = (const uint4*)Wt;
    #pragma unroll
    for (int j = 0; j < 8; ++j) {
        int i = threadIdx.x + j * 256;   // 0..2047: row = i>>4, 16B-seg = i&15
        int r = i >> 4, s16 = i & 15;
        *(uint4*)&WtS[r * 136 + s16 * 8] = wsrc[i];
    }

    int wv   = threadIdx.x >> 6;
    int lane = threadIdx.x & 63;
    int m16  = lane & 15;
    int kq   = lane >> 4;
    int rowbase = blockIdx.x * 128 + wv * 32;

    // preload A-frags: 2 m-tiles x 4 k-steps
    bf16x8 a0[4], a1[4];
    #pragma unroll
    for (int ks = 0; ks < 4; ++ks) {
        int kb = ks * 32 + kq * 8;
        a0[ks] = load_frag(A, rowbase + m16, kb, n, pre_scale, pre_shift);
        a1[ks] = load_frag(A, rowbase + 16 + m16, kb, n, pre_scale, pre_shift);
    }

    f32x4 acc0[8], acc1[8];
    #pragma unroll
    for (int t = 0; t < 8; ++t) {
        acc0[t] = (f32x4){0.f, 0.f, 0.f, 0.f};
        acc1[t] = (f32x4){0.f, 0.f, 0.f, 0.f};
    }
    __syncthreads();

    #pragma unroll
    for (int ks = 0; ks < 4; ++ks) {
        #pragma unroll
        for (int t = 0; t < 8; ++t) {
            bf16x8 b = *(const bf16x8*)&WtS[(t * 16 + m16) * 136 + ks * 32 + kq * 8];
            acc0[t] = __builtin_amdgcn_mfma_f32_16x16x32_bf16(a0[ks], b, acc0[t], 0, 0, 0);
            acc1[t] = __builtin_amdgcn_mfma_f32_16x16x32_bf16(a1[ks], b, acc1[t], 0, 0, 0);
        }
    }

    // epilogue: bias, bf16 store, fused column stats
    int slot = blockIdx.x & (NSLOT - 1);
    #pragma unroll
    for (int t = 0; t < 8; ++t) {
        int col = t * 16 + m16;
        float bz = bias[col];
        float s = 0.f, q = 0.f;
        #pragma unroll
        for (int mt = 0; mt < 2; ++mt) {
            f32x4 v4 = mt ? acc1[t] : acc0[t];
            #pragma unroll
            for (int rr = 0; rr < 4; ++rr) {
                int row = rowbase + mt * 16 + kq * 4 + rr;
                if (row < n) {
                    float v = v4[rr] + bz;
                    C[(size_t)row * D + col] = f2b(v);
                    s += v; q += v * v;
                }
            }
        }
        s += __shfl_xor(s, 16); q += __shfl_xor(q, 16);
        s += __shfl_xor(s, 32); q += __shfl_xor(q, 32);
        if (kq == 0) {
            atomicAdd(&stats[slot * 256 + col], s);
            atomicAdd(&stats[slot * 256 + 128 + col], q);
        }
    }
}

// ---------------------------------------------------------------- BN param fold
__global__ void k_bnparams(const float* __restrict__ stats, const float* __restrict__ gamma,
                           const float* __restrict__ beta, float* __restrict__ scale,
                           float* __restrict__ shift, float inv_n) {
    int c = threadIdx.x;  // 128 threads
    float s = 0.f, q = 0.f;
    for (int sl = 0; sl < NSLOT; ++sl) {
        s += stats[sl * 256 + c];
        q += stats[sl * 256 + 128 + c];
    }
    float mu  = s * inv_n;
    float var = q * inv_n - mu * mu;
    var = var < 0.f ? 0.f : var;
    float rs = rsqrtf(var + 1e-5f);
    float sc = gamma[c] * rs;
    scale[c] = sc;
    shift[c] = beta[c] - mu * sc;
}

// ---------------------------------------------------------------- BN apply (+relu)
// mode 0: bf16 out + relu;  mode 1: fp32 out, no relu (final layer)
__global__ __launch_bounds__(256)
void k_final(const unsigned* __restrict__ z, const float* __restrict__ scale,
             const float* __restrict__ shift, int mode,
             unsigned* __restrict__ outb, float* __restrict__ outf, int total2) {
    int i = blockIdx.x * 256 + threadIdx.x;  // index of uint2 = 4 bf16
    if (i >= total2) return;
    uint2 u = ((const uint2*)z)[i];
    int c = (i * 4) & (D - 1);
    float v0 = b2f_lo(u.x) * scale[c + 0] + shift[c + 0];
    float v1 = b2f_hi(u.x) * scale[c + 1] + shift[c + 1];
    float v2 = b2f_lo(u.y) * scale[c + 2] + shift[c + 2];
    float v3 = b2f_hi(u.y) * scale[c + 3] + shift[c + 3];
    if (mode == 0) {
        v0 = v0 > 0.f ? v0 : 0.f;
        v1 = v1 > 0.f ? v1 : 0.f;
        v2 = v2 > 0.f ? v2 : 0.f;
        v3 = v3 > 0.f ? v3 : 0.f;
        uint2 o;
        o.x = (unsigned)f2b(v0) | ((unsigned)f2b(v1) << 16);
        o.y = (unsigned)f2b(v2) | ((unsigned)f2b(v3) << 16);
        ((uint2*)outb)[i] = o;
    } else {
        float4 o;
        o.x = v0; o.y = v1; o.z = v2; o.w = v3;
        ((float4*)outf)[i] = o;
    }
}

// ---------------------------------------------------------------- launch
extern "C" void kernel_launch(void* const* d_in, const int* in_sizes, int n_in,
                              void* d_out, int out_size, void* d_ws, size_t ws_size,
                              hipStream_t stream) {
    const float* x   = (const float*)d_in[0];
    const int*   ei  = (const int*)d_in[1];
    const float* W1  = (const float*)d_in[4];
    const float* b1  = (const float*)d_in[5];
    const float* g1  = (const float*)d_in[6];
    const float* be1 = (const float*)d_in[7];
    const float* W2  = (const float*)d_in[8];
    const float* b2  = (const float*)d_in[9];
    const float* g2  = (const float*)d_in[10];
    const float* be2 = (const float*)d_in[11];

    const int* srcI = ei;             // edge_index[0]
    const int* dstI = ei + N_EDGES;   // edge_index[1]

    // workspace layout (~60 MB)
    char* ws = (char*)d_ws;
    unsigned* bufA = (unsigned*)ws; ws += (size_t)N_NODES * 64 * 4 + 65536;
    unsigned* bufB = (unsigned*)ws; ws += (size_t)N_NODES * 64 * 4 + 65536;
    int* csrc    = (int*)ws;   ws += (size_t)N_EDGES * 4;
    int* deg     = (int*)ws;   ws += (size_t)N_NODES * 4;
    int* offs    = (int*)ws;   ws += (size_t)N_NODES * 4;
    int* cursor  = (int*)ws;   ws += (size_t)N_NODES * 4;
    int* bsum    = (int*)ws;   ws += 512;
    ushort* Wt1  = (ushort*)ws; ws += 3 * D * D * 2;
    ushort* Wt2  = (ushort*)ws; ws += 3 * D * D * 2;
    float* stats = (float*)ws; ws += NSLOT * 256 * 4;
    float* scale1 = (float*)ws; ws += 512;
    float* shift1 = (float*)ws; ws += 512;
    float* scale2 = (float*)ws; ws += 512;
    float* shift2 = (float*)ws; ws += 512;

    // ---- weight prep (fp32 -> transposed bf16) ----
    k_wprep<<<dim3(D, 3), D, 0, stream>>>(W1, Wt1);
    k_wprep<<<dim3(D, 3), D, 0, stream>>>(W2, Wt2);

    // ---- CSR build ----
    k_zero_i32<<<(N_NODES + 255) / 256, 256, 0, stream>>>(deg, N_NODES);
    k_hist<<<(N_EDGES + 255) / 256, 256, 0, stream>>>(dstI, deg, N_EDGES);
    int nsb = (N_NODES + 1023) / 1024;  // 98
    k_scan_partial<<<nsb, 256, 0, stream>>>(deg, bsum, N_NODES);
    k_scan_top<<<1, 128, 0, stream>>>(bsum, nsb);
    k_scan_final<<<nsb, 256, 0, stream>>>(deg, bsum, offs, cursor, N_NODES);
    k_scatter<<<(N_EDGES + 255) / 256, 256, 0, stream>>>(srcI, dstI, cursor, csrc, N_EDGES);

    const float inv_n = 1.0f / (float)N_NODES;
    int ngemm = (N_NODES + 127) / 128;  // 782
    int nfin  = (N_NODES * D / 4 + 255) / 256;

    for (int l = 0; l < NLAYER; ++l) {
        // agg: h -> bufA (bf16)
        if (l == 0)
            k_agg_f32<<<(N_NODES + 3) / 4, 256, 0, stream>>>(x, offs, deg, csrc, bufA, N_NODES);
        else
            k_agg_b16<<<(N_NODES + 3) / 4, 256, 0, stream>>>(bufB, offs, deg, csrc, bufA, N_NODES);
        // z1 = bufA @ W1 + b1  -> bufB (bf16), fused col stats
        k_zero_i32<<<NSLOT, 256, 0, stream>>>((int*)stats, NSLOT * 256);
        k_gemm<<<ngemm, 256, 0, stream>>>(
            (const ushort*)bufA, Wt1 + (size_t)l * D * D, b1 + l * D,
            nullptr, nullptr, (ushort*)bufB, stats, N_NODES);
        k_bnparams<<<1, D, 0, stream>>>(stats, g1 + l * D, be1 + l * D, scale1, shift1, inv_n);
        // z2 = relu(bn1(z1)) @ W2 + b2 -> bufA (bf16), affine fused in A-frag load
        k_zero_i32<<<NSLOT, 256, 0, stream>>>((int*)stats, NSLOT * 256);
        k_gemm<<<ngemm, 256, 0, stream>>>(
            (const ushort*)bufB, Wt2 + (size_t)l * D * D, b2 + l * D,
            scale1, shift1, (ushort*)bufA, stats, N_NODES);
        k_bnparams<<<1, D, 0, stream>>>(stats, g2 + l * D, be2 + l * D, scale2, shift2, inv_n);
        // h' = bn2(z2) (+relu except last): bufA -> bufB (bf16) or d_out (fp32)
        if (l < NLAYER - 1)
            k_final<<<nfin, 256, 0, stream>>>(bufA, scale2, shift2, 0, bufB, nullptr, N_NODES * D / 4);
        else
            k_final<<<nfin, 256, 0, stream>>>(bufA, scale2, shift2, 1, nullptr, (float*)d_out, N_NODES * D / 4);
    }
}